// Round 4
// baseline (504.315 us; speedup 1.0000x reference)
//
#include <hip/hip_runtime.h>
#include <math.h>

// ---------------------------------------------------------------------------
// ActorNetwork forward, MI355X (gfx950). Round 4: one fused kernel,
// 16 rows/block x 4096 blocks, 39424 B LDS -> 4 blocks/CU (16 waves/CU).
// Env GEMM (256 MB stream) fused with 8-deep rolling A prefetch issued before
// the VALU encoder phase so load latency hides under compute.
// ---------------------------------------------------------------------------

typedef float f32x4 __attribute__((ext_vector_type(4)));
typedef float f32x4u __attribute__((ext_vector_type(4), aligned(4)));
typedef float f32x2u __attribute__((ext_vector_type(2), aligned(4)));
typedef __bf16 bf16x8 __attribute__((ext_vector_type(8)));
typedef unsigned short u16x8 __attribute__((ext_vector_type(8)));

#define DI __device__ __forceinline__

DI unsigned short f2bf_u(float f) {  // fp32 -> bf16 bits, RTNE
  unsigned u = __builtin_bit_cast(unsigned, f);
  u += 0x7fffu + ((u >> 16) & 1u);
  return (unsigned short)(u >> 16);
}
DI float bfu2f(unsigned short s) {
  unsigned u = ((unsigned)s) << 16;
  return __builtin_bit_cast(float, u);
}
DI u16x8 cvt8(f32x4 x, f32x4 y) {  // v_cvt_pk_bf16_f32 on gfx950
  bf16x8 r;
  r[0] = (__bf16)x[0]; r[1] = (__bf16)x[1]; r[2] = (__bf16)x[2]; r[3] = (__bf16)x[3];
  r[4] = (__bf16)y[0]; r[5] = (__bf16)y[1]; r[6] = (__bf16)y[2]; r[7] = (__bf16)y[3];
  return __builtin_bit_cast(u16x8, r);
}
DI f32x4 mfma16(u16x8 a, u16x8 b, f32x4 c) {
  return __builtin_amdgcn_mfma_f32_16x16x32_bf16(
      __builtin_bit_cast(bf16x8, a), __builtin_bit_cast(bf16x8, b), c, 0, 0, 0);
}

// Fragment layouts (learn_hip m89/m91):
//   A-frag: lane l holds A[m = l&15][k = (l>>4)*8 + j], j=0..7
//   B-frag: lane l holds B[k = (l>>4)*8 + j][n = l&15]
//   C/D   : lane l holds C[row = (l>>4)*4 + ri][col = l&15]
// Packed frag buffers: u16x8[(kt*NT + nt)*64 + lane].

// ---- workspace layout (bytes) ----
constexpr size_t WS_WGF = 0;        // Wg frags  [32kt][4nt]   131072
constexpr size_t WS_WS2 = 131072;   // Ws2 frags [2][4]          8192
constexpr size_t WS_WV  = 139264;   // Wv frags  [2][4]          8192
constexpr size_t WS_MQK = 147456;   // Mqk frags [2][4]          8192
constexpr size_t WS_WC1 = 155648;   // Wc1 frags [6][8]         49152
constexpr size_t WS_WC2 = 204800;   // Wc2 frags [4][8]         32768

// ---------------------------------------------------------------------------
// k_prep: pack all weights into bf16 B-frag layout; M_qk = Wq@Wk^T inline.
// ---------------------------------------------------------------------------
__global__ __launch_bounds__(256) void k_prep(
    const float* __restrict__ Wg, const float* __restrict__ Ws2,
    const float* __restrict__ Wv, const float* __restrict__ Wq,
    const float* __restrict__ Wk, const float* __restrict__ Wc1,
    const float* __restrict__ Wc2,
    unsigned short* __restrict__ wgf, unsigned short* __restrict__ ws2f,
    unsigned short* __restrict__ wvf, unsigned short* __restrict__ mqkf,
    unsigned short* __restrict__ wc1f, unsigned short* __restrict__ wc2f) {
  const int idx = blockIdx.x * 256 + threadIdx.x;  // 118784 total
  const float* src = nullptr;
  unsigned short* dst;
  int i, ntm, NC;
  bool is_mqk = false;
  if (idx < 65536)      { src = Wg;  dst = wgf;  i = idx;          ntm = 2; NC = 64;  }
  else if (idx < 69632) { src = Ws2; dst = ws2f; i = idx - 65536;  ntm = 2; NC = 64;  }
  else if (idx < 73728) { src = Wv;  dst = wvf;  i = idx - 69632;  ntm = 2; NC = 64;  }
  else if (idx < 77824) { is_mqk = true; dst = mqkf; i = idx - 73728; ntm = 2; NC = 64; }
  else if (idx < 102400){ src = Wc1; dst = wc1f; i = idx - 77824;  ntm = 3; NC = 128; }
  else                  { src = Wc2; dst = wc2f; i = idx - 102400; ntm = 3; NC = 128; }
  const int j = i & 7, ln = (i >> 3) & 63, t2 = i >> 9;
  const int nt = t2 & ((1 << ntm) - 1), kt = t2 >> ntm;
  const int k = kt * 32 + (ln >> 4) * 8 + j, n = nt * 16 + (ln & 15);
  float val;
  if (is_mqk) {
    const f32x4* qp = (const f32x4*)(Wq + k * 64);
    const f32x4* kp = (const f32x4*)(Wk + n * 64);
    float acc = 0.f;
#pragma unroll
    for (int d4 = 0; d4 < 16; ++d4) {
      const f32x4 a = qp[d4], b = kp[d4];
#pragma unroll
      for (int e = 0; e < 4; ++e) acc = fmaf(a[e], b[e], acc);
    }
    val = acc;
  } else {
    val = src[k * NC + n];
  }
  dst[i] = f2bf_u(val);
}

// ---------------------------------------------------------------------------
// k_main: whole network, 16 batch rows/block, 4096 blocks x 256 threads.
// ---------------------------------------------------------------------------
__global__ __launch_bounds__(256, 4) void k_main(
    const float* __restrict__ s0, const float* __restrict__ s1,
    const float* __restrict__ s2,
    const float* __restrict__ W0, const float* __restrict__ b0v,
    const float* __restrict__ bg,
    const float* __restrict__ Ws1, const float* __restrict__ bs1,
    const unsigned short* __restrict__ ws2f, const float* __restrict__ bs2,
    const unsigned short* __restrict__ wvf, const unsigned short* __restrict__ mqkf,
    const unsigned short* __restrict__ wc1f, const float* __restrict__ bc1,
    const unsigned short* __restrict__ wc2f, const float* __restrict__ bc2,
    const float* __restrict__ Wc3, const float* __restrict__ bc3,
    const unsigned short* __restrict__ wgf,
    float* __restrict__ out) {
  // LDS map (39424 B -> 4 blocks/CU):
  //  [0,16384)     EF  : E1/E2 frags [8mt][2kt][64] u16x8
  //  [16384,22528) CF  : concat frags [6kt][64] (kt 0,1 own; 2,3 env; 4,5 vatt)
  //  [22528,38912) SCR : time-multiplexed scratch:
  //                 RED f32x4[16][64] (env partials)          [0,16384)
  //                 QK fp32 [16][64]                          [0,4096)
  //                 SEF sE2 frags [2kt][64]                   [0,2048)
  //                 H1F h1 frags [4kt][64]                    [0,4096)
  //                 H2 fp32 [16][132]                         [4096,12544)
  //  [38912,39424) SC  : scores->alpha fp32 [128]
  __shared__ __align__(16) char smem[39424];
  u16x8* EF = (u16x8*)smem;
  unsigned short* EFs = (unsigned short*)smem;
  u16x8* CF = (u16x8*)(smem + 16384);
  unsigned short* CFs = (unsigned short*)(smem + 16384);
  char* SCR = smem + 22528;
  f32x4* RED4 = (f32x4*)SCR;
  float* QK = (float*)SCR;
  u16x8* SEF = (u16x8*)SCR;
  u16x8* H1F = (u16x8*)SCR;
  unsigned short* H1Fs = (unsigned short*)SCR;
  float* H2 = (float*)(SCR + 4096);
  float* SC = (float*)(smem + 38912);

  const int tid = threadIdx.x;
  const int lane = tid & 63, wave = tid >> 6;
  const int lo = lane & 15, q = lane >> 4;
  const int bbase = blockIdx.x * 16;

  // ---- 1) issue env A-stream first: rolling 8-deep (4 ks-steps ahead) ----
  const float* arow = s1 + (size_t)(bbase + lo) * 1024 + wave * 256 + q * 8;
  f32x4 Ab0[4], Ab1[4];
#pragma unroll
  for (int i = 0; i < 4; ++i) {
    Ab0[i] = *(const f32x4*)(arow + i * 32);
    Ab1[i] = *(const f32x4*)(arow + i * 32 + 4);
  }
  const u16x8* wp = (const u16x8*)wgf + lane;
  u16x8 Bb[2][4];
#pragma unroll
  for (int nt = 0; nt < 4; ++nt) Bb[0][nt] = wp[((wave * 8) * 4 + nt) * 64];

  // ---- 2) issue s2/s0 loads ----
  const int ir = tid >> 1, half = tid & 1;      // intruder row 0..127, col-half
  const int ibl = ir >> 3, in_ = ir & 7;        // batch row, neighbor
  const float* s2p = s2 + ((size_t)(bbase + ibl) * 8 + in_) * 7;
  const f32x4u x03 = *(const f32x4u*)s2p;
  const f32x2u x45 = *(const f32x2u*)(s2p + 4);
  const float x6 = s2p[6];
  const int orow = tid >> 3, oc = tid & 7;      // own_e: row 0..15 (t<128), col-chunk
  const float* s0p = s0 + (size_t)(bbase + orow) * 6;
  f32x4u y03 = {};
  f32x2u y45 = {};
  if (tid < 128) {
    y03 = *(const f32x4u*)s0p;
    y45 = *(const f32x2u*)(s0p + 4);
  }

  // ---- Phase A: E1 = relu(state2 @ Ws1 + bs1), K=7 VALU (under env loads) --
  bool maskreg;
  {
    float xv[7] = {x03[0], x03[1], x03[2], x03[3], x45[0], x45[1], x6};
    const float sum = xv[0] + xv[1] + xv[2] + xv[3] + xv[4] + xv[5] + xv[6];
    maskreg = (sum != 0.f);  // padded slots are exact zeros
    const int mt = ir >> 4, rl = ir & 15;
#pragma unroll
    for (int cc = 0; cc < 4; ++cc) {
      const int c = half * 4 + cc;
      float a[8];
#pragma unroll
      for (int i = 0; i < 8; ++i) a[i] = bs1[c * 8 + i];
#pragma unroll
      for (int j = 0; j < 7; ++j) {
        const float* wr = Ws1 + j * 64 + c * 8;
#pragma unroll
        for (int i = 0; i < 8; ++i) a[i] = fmaf(xv[j], wr[i], a[i]);
      }
      u16x8 pk;
#pragma unroll
      for (int i = 0; i < 8; ++i) pk[i] = f2bf_u(fmaxf(a[i], 0.f));
      EF[(mt * 2 + half) * 64 + ((cc << 4) | rl)] = pk;
    }
  }

  // ---- Phase ENV: K-loop (loads mostly landed during Phase A) ----
  {
    f32x4 acc[4] = {};
#pragma unroll
    for (int ks = 0; ks < 8; ++ks) {
      const int cur = ks & 1;
      if (ks < 7) {
#pragma unroll
        for (int nt = 0; nt < 4; ++nt)
          Bb[cur ^ 1][nt] = wp[((wave * 8 + ks + 1) * 4 + nt) * 64];
      }
      const u16x8 af = cvt8(Ab0[ks & 3], Ab1[ks & 3]);
      if (ks < 4) {  // rolling prefetch: ks+4 into the slot just consumed
        Ab0[ks] = *(const f32x4*)(arow + (ks + 4) * 32);
        Ab1[ks] = *(const f32x4*)(arow + (ks + 4) * 32 + 4);
      }
#pragma unroll
      for (int nt = 0; nt < 4; ++nt) acc[nt] = mfma16(af, Bb[cur][nt], acc[nt]);
    }
#pragma unroll
    for (int nt = 0; nt < 4; ++nt) RED4[(wave * 4 + nt) * 64 + lane] = acc[nt];
  }
  __syncthreads();  // barrier 1: EF (Phase A) + RED (env partials)

  // ---- env reduce: wave w owns col tile nt=w; write CF env frags kt 2,3 ----
  {
    f32x4 s = RED4[(0 * 4 + wave) * 64 + lane];
#pragma unroll
    for (int pp = 1; pp < 4; ++pp) s += RED4[(pp * 4 + wave) * 64 + lane];
    const float bias = bg[wave * 16 + lo];
    const int h = wave * 16 + lo;
#pragma unroll
    for (int ri = 0; ri < 4; ++ri) {
      const float v = fmaxf(s[ri] + bias, 0.f);
      CFs[((2 + (h >> 5)) * 64 + ((((h >> 3) & 3) << 4) | (q * 4 + ri))) * 8 +
          (h & 7)] = f2bf_u(v);
    }
  }

  // ---- Phase B: E2 = relu(E1 @ Ws2 + bs2), in-place frag overwrite ----
  {
    u16x8 Bf[4][2];
#pragma unroll
    for (int nt = 0; nt < 4; ++nt)
#pragma unroll
      for (int kt = 0; kt < 2; ++kt)
        Bf[nt][kt] = ((const u16x8*)ws2f)[(kt * 4 + nt) * 64 + lane];
    float bias[4];
#pragma unroll
    for (int nt = 0; nt < 4; ++nt) bias[nt] = bs2[nt * 16 + lo];
#pragma unroll
    for (int mi = 0; mi < 2; ++mi) {  // wave owns mtiles wave*2..+1
      const int mt = wave * 2 + mi;
      const u16x8 A0 = EF[(mt * 2 + 0) * 64 + lane];
      const u16x8 A1 = EF[(mt * 2 + 1) * 64 + lane];
      f32x4 acc[4] = {};
#pragma unroll
      for (int nt = 0; nt < 4; ++nt) {
        acc[nt] = mfma16(A0, Bf[nt][0], acc[nt]);
        acc[nt] = mfma16(A1, Bf[nt][1], acc[nt]);
      }
#pragma unroll
      for (int nt = 0; nt < 4; ++nt) {
        const int h = nt * 16 + lo;
#pragma unroll
        for (int ri = 0; ri < 4; ++ri) {
          const float v = fmaxf(acc[nt][ri] + bias[nt], 0.f);
          const int rr = mt * 16 + q * 4 + ri;
          EFs[((mt * 2 + (h >> 5)) * 64 + ((((h >> 3) & 3) << 4) | (rr & 15))) * 8 +
              (h & 7)] = f2bf_u(v);
        }
      }
    }
  }

  // ---- Phase C1: own_e = relu(s0 @ W0 + b0) -> CF kt 0,1 (t<128) ----
  if (tid < 128) {
    const float yv[6] = {y03[0], y03[1], y03[2], y03[3], y45[0], y45[1]};
    float a[8];
#pragma unroll
    for (int i = 0; i < 8; ++i) a[i] = b0v[oc * 8 + i];
#pragma unroll
    for (int j = 0; j < 6; ++j) {
      const float* wr = W0 + j * 64 + oc * 8;
#pragma unroll
      for (int i = 0; i < 8; ++i) a[i] = fmaf(yv[j], wr[i], a[i]);
    }
    u16x8 pk;
#pragma unroll
    for (int i = 0; i < 8; ++i) pk[i] = f2bf_u(fmaxf(a[i], 0.f));
    CF[(oc >> 2) * 64 + (((oc & 3) << 4) | orow)] = pk;
  }
  __syncthreads();  // barrier 2: CF own frags; RED dead from here

  // ---- Phase C2: qk = own_e @ M_qk (wave nt=wave) -> QK fp32 [16][64] ----
  {
    const u16x8 A0 = CF[0 * 64 + lane];
    const u16x8 A1 = CF[1 * 64 + lane];
    const u16x8 B0 = ((const u16x8*)mqkf)[(0 * 4 + wave) * 64 + lane];
    const u16x8 B1 = ((const u16x8*)mqkf)[(1 * 4 + wave) * 64 + lane];
    f32x4 acc = {};
    acc = mfma16(A0, B0, acc);
    acc = mfma16(A1, B1, acc);
#pragma unroll
    for (int ri = 0; ri < 4; ++ri)
      QK[(q * 4 + ri) * 64 + wave * 16 + lo] = acc[ri];
  }
  __syncthreads();  // barrier 3

  // ---- Phase C3: score_ir = (E2_ir . qk_bl)/8, 2 threads/row + shfl ----
  {
    const int rl = ir & 15, mt = ir >> 4;
    float dot = 0.f;
#pragma unroll
    for (int cc = 0; cc < 4; ++cc) {
      const int c = half * 4 + cc;
      const u16x8 e = EF[(mt * 2 + half) * 64 + ((cc << 4) | rl)];
      const float* qkp = QK + ibl * 64 + c * 8;
      const f32x4 qa = *(const f32x4*)(qkp);
      const f32x4 qb = *(const f32x4*)(qkp + 4);
#pragma unroll
      for (int i = 0; i < 4; ++i) dot = fmaf(bfu2f(e[i]), qa[i], dot);
#pragma unroll
      for (int i = 0; i < 4; ++i) dot = fmaf(bfu2f(e[4 + i]), qb[i], dot);
    }
    dot += __shfl_xor(dot, 1);
    if (half == 0) SC[ir] = maskreg ? dot * 0.125f : -1e30f;  // 1/sqrt(64)
  }
  __syncthreads();  // barrier 4

  // ---- Phase C4: softmax over N=8, in place in SC (t<16) ----
  if (tid < 16) {
    float s[8];
#pragma unroll
    for (int n = 0; n < 8; ++n) s[n] = SC[tid * 8 + n];
    float mx = s[0];
#pragma unroll
    for (int n = 1; n < 8; ++n) mx = fmaxf(mx, s[n]);
    float e[8], sum = 0.f;
#pragma unroll
    for (int n = 0; n < 8; ++n) { e[n] = __expf(s[n] - mx); sum += e[n]; }
    const float inv = 1.f / sum;
#pragma unroll
    for (int n = 0; n < 8; ++n) SC[tid * 8 + n] = e[n] * inv;
  }
  __syncthreads();  // barrier 5; QK dead from here

  // ---- Phase C5: sE2_b = sum_n alpha_n * E2_{b,n} -> SEF frags (t<128) ----
  if (tid < 128) {
    const int bl = tid >> 3, cch = tid & 7;
    float al[8];
#pragma unroll
    for (int n = 0; n < 8; ++n) al[n] = SC[bl * 8 + n];
    float a[8] = {0.f, 0.f, 0.f, 0.f, 0.f, 0.f, 0.f, 0.f};
#pragma unroll
    for (int n = 0; n < 8; ++n) {
      const int rr = bl * 8 + n;
      const u16x8 e =
          EF[((rr >> 4) * 2 + (cch >> 2)) * 64 + (((cch & 3) << 4) | (rr & 15))];
#pragma unroll
      for (int i = 0; i < 8; ++i) a[i] = fmaf(al[n], bfu2f(e[i]), a[i]);
    }
    u16x8 pk;
#pragma unroll
    for (int i = 0; i < 8; ++i) pk[i] = f2bf_u(a[i]);
    SEF[(cch >> 2) * 64 + (((cch & 3) << 4) | bl)] = pk;
  }
  __syncthreads();  // barrier 6

  // ---- Phase C6: v_att = sE2 @ Wv (wave nt=wave) -> CF kt 4,5 ----
  {
    const u16x8 A0 = SEF[0 * 64 + lane];
    const u16x8 A1 = SEF[1 * 64 + lane];
    const u16x8 B0 = ((const u16x8*)wvf)[(0 * 4 + wave) * 64 + lane];
    const u16x8 B1 = ((const u16x8*)wvf)[(1 * 4 + wave) * 64 + lane];
    f32x4 acc = {};
    acc = mfma16(A0, B0, acc);
    acc = mfma16(A1, B1, acc);
    const int h = wave * 16 + lo;
#pragma unroll
    for (int ri = 0; ri < 4; ++ri) {
      const int rr = q * 4 + ri;
      CFs[((4 + (h >> 5)) * 64 + ((((h >> 3) & 3) << 4) | rr)) * 8 + (h & 7)] =
          f2bf_u(acc[ri]);
    }
  }
  __syncthreads();  // barrier 7; SEF dead from here

  // ---- Phase D1: h1 = relu(concat @ Wc1 + bc1), K=192; wave -> 2 nt ----
  {
    u16x8 A[6];
#pragma unroll
    for (int kt = 0; kt < 6; ++kt) A[kt] = CF[kt * 64 + lane];
#pragma unroll
    for (int ni = 0; ni < 2; ++ni) {
      const int nt = wave * 2 + ni;
      f32x4 acc = {};
#pragma unroll
      for (int kt = 0; kt < 6; ++kt) {
        const u16x8 Bf = ((const u16x8*)wc1f)[(kt * 8 + nt) * 64 + lane];
        acc = mfma16(A[kt], Bf, acc);
      }
      const float bias = bc1[nt * 16 + lo];
      const int h = nt * 16 + lo;
#pragma unroll
      for (int ri = 0; ri < 4; ++ri) {
        const float v = fmaxf(acc[ri] + bias, 0.f);
        const int rr = q * 4 + ri;
        H1Fs[((h >> 5) * 64 + ((((h >> 3) & 3) << 4) | rr)) * 8 + (h & 7)] =
            f2bf_u(v);
      }
    }
  }
  __syncthreads();  // barrier 8

  // ---- Phase D2: h2 = relu(h1 @ Wc2 + bc2) -> H2 fp32 [16][132] ----
  {
    u16x8 A[4];
#pragma unroll
    for (int kt = 0; kt < 4; ++kt) A[kt] = H1F[kt * 64 + lane];
#pragma unroll
    for (int ni = 0; ni < 2; ++ni) {
      const int nt = wave * 2 + ni;
      f32x4 acc = {};
#pragma unroll
      for (int kt = 0; kt < 4; ++kt) {
        const u16x8 Bf = ((const u16x8*)wc2f)[(kt * 8 + nt) * 64 + lane];
        acc = mfma16(A[kt], Bf, acc);
      }
      const float bias = bc2[nt * 16 + lo];
#pragma unroll
      for (int ri = 0; ri < 4; ++ri)
        H2[(q * 4 + ri) * 132 + nt * 16 + lo] = fmaxf(acc[ri] + bias, 0.f);
    }
  }
  __syncthreads();  // barrier 9

  // ---- Phase D3: out = tanh(h2 @ Wc3 + bc3), fp32, 8 threads per output ----
  {
    const int row = tid >> 4, a = (tid >> 3) & 1, kseg = tid & 7;
    const f32x4* h4 = (const f32x4*)(H2 + row * 132 + kseg * 16);
    const float* wr = Wc3 + kseg * 32;  // Wc3[h][2], h = kseg*16 + j
    float acc = 0.f;
#pragma unroll
    for (int j4 = 0; j4 < 4; ++j4) {
      const f32x4 hv = h4[j4];
#pragma unroll
      for (int e = 0; e < 4; ++e) acc = fmaf(hv[e], wr[(j4 * 4 + e) * 2 + a], acc);
    }
    acc += __shfl_down(acc, 1);
    acc += __shfl_down(acc, 2);
    acc += __shfl_down(acc, 4);
    if (kseg == 0) out[(size_t)(bbase + row) * 2 + a] = tanhf(acc + bc3[a]);
  }
}

// ---------------------------------------------------------------------------
extern "C" void kernel_launch(void* const* d_in, const int* in_sizes, int n_in,
                              void* d_out, int out_size, void* d_ws, size_t ws_size,
                              hipStream_t stream) {
  const float* s0  = (const float*)d_in[0];
  const float* s1  = (const float*)d_in[1];
  const float* s2  = (const float*)d_in[2];
  const float* W0  = (const float*)d_in[3];
  const float* b0  = (const float*)d_in[4];
  const float* Wg  = (const float*)d_in[5];
  const float* bg  = (const float*)d_in[6];
  const float* Ws1 = (const float*)d_in[7];
  const float* bs1 = (const float*)d_in[8];
  const float* Ws2 = (const float*)d_in[9];
  const float* bs2 = (const float*)d_in[10];
  const float* Wq  = (const float*)d_in[11];
  const float* Wk  = (const float*)d_in[12];
  const float* Wv  = (const float*)d_in[13];
  const float* Wc1 = (const float*)d_in[14];
  const float* bc1 = (const float*)d_in[15];
  const float* Wc2 = (const float*)d_in[16];
  const float* bc2 = (const float*)d_in[17];
  const float* Wc3 = (const float*)d_in[18];
  const float* bc3 = (const float*)d_in[19];

  char* ws = (char*)d_ws;
  unsigned short* wgf  = (unsigned short*)(ws + WS_WGF);
  unsigned short* ws2f = (unsigned short*)(ws + WS_WS2);
  unsigned short* wvf  = (unsigned short*)(ws + WS_WV);
  unsigned short* mqkf = (unsigned short*)(ws + WS_MQK);
  unsigned short* wc1f = (unsigned short*)(ws + WS_WC1);
  unsigned short* wc2f = (unsigned short*)(ws + WS_WC2);

  hipLaunchKernelGGL(k_prep, dim3(464), dim3(256), 0, stream, Wg, Ws2, Wv, Wq,
                     Wk, Wc1, Wc2, wgf, ws2f, wvf, mqkf, wc1f, wc2f);
  hipLaunchKernelGGL(k_main, dim3(4096), dim3(256), 0, stream, s0, s1, s2, W0,
                     b0, bg, Ws1, bs1, ws2f, bs2, wvf, mqkf, wc1f, bc1, wc2f,
                     bc2, Wc3, bc3, wgf, (float*)d_out);
}